// Round 4
// baseline (574.136 us; speedup 1.0000x reference)
//
#include <hip/hip_runtime.h>
#include <math.h>

// MoE FFN: top-2 of 8 experts + shared expert, H=1024, F=2048, N=4096.
// Round 7: deep prefetch rings (BK=32 sub-buffers).
//  - gateup: 4-deep ring {A,Bg,Bu}, issue X-3, drain X-1 -> 4-5 phase cover,
//    vmcnt(8) once per buffer. LDS 129KB (same as R6).
//  - down: 6-deep ring, issue X-5, drain X-1, vmcnt(12). LDS 146KB.
//  - swizzle for 64B rows: phys slot = q ^ ((row>>1)&3); src pre-swizzle
//    (l&3)^((l>>3)&3); read slot quad^((lm>>1)&3). 2 lanes/16B-slot = free.
// R6 post-mortem: conflicts 9.7M->0 (T2 confirmed) but prefetch distance was
// only 1-3 phases -> latency still exposed; MfmaUtil 30.5%. This fixes depth.

#define H_DIM 1024
#define F_DIM 2048
#define E_NUM 8
#define EPSV 1e-9f

typedef __bf16 bf16x8 __attribute__((ext_vector_type(8)));
typedef float f32x4 __attribute__((ext_vector_type(4)));

#define MFMA16(a, b, c) __builtin_amdgcn_mfma_f32_16x16x32_bf16(a, b, c, 0, 0, 0)

__device__ __forceinline__ unsigned f2bf(float f) {
    unsigned u = __float_as_uint(f);
    return (u + 0x7FFFu + ((u >> 16) & 1u)) >> 16;  // RNE
}

// async global->LDS, 16B per lane; lds ptr must be wave-uniform
__device__ __forceinline__ void gload16(const ushort* g, ushort* l) {
    __builtin_amdgcn_global_load_lds(
        (__attribute__((address_space(1))) void*)(void*)const_cast<ushort*>(g),
        (__attribute__((address_space(3))) void*)l, 16, 0, 0);
}

#define PHASE_SYNC_PRE()                                      \
    __builtin_amdgcn_s_barrier();                             \
    asm volatile("s_waitcnt lgkmcnt(0)" ::: "memory");        \
    __builtin_amdgcn_sched_barrier(0);                        \
    __builtin_amdgcn_s_setprio(1);

#define PHASE_SYNC_POST()                                     \
    __builtin_amdgcn_s_setprio(0);                            \
    __builtin_amdgcn_s_barrier();

// ---------------- Y zeroing (atomic-accumulate target) ----------------
__global__ void zero_kernel(float4* __restrict__ p, int n4) {
    int i = blockIdx.x * 256 + threadIdx.x;
    if (i < n4) p[i] = make_float4(0.f, 0.f, 0.f, 0.f);
}

// ---------------- fp32 -> bf16 conversion (8 elems/thread) ----------------
__global__ void cvt_bf16_kernel(const float* __restrict__ src, ushort* __restrict__ dst, int n8) {
    int i = blockIdx.x * 256 + threadIdx.x;
    if (i >= n8) return;
    float4 a = ((const float4*)src)[2 * i];
    float4 b = ((const float4*)src)[2 * i + 1];
    uint4 o;
    o.x = f2bf(a.x) | (f2bf(a.y) << 16);
    o.y = f2bf(a.z) | (f2bf(a.w) << 16);
    o.z = f2bf(b.x) | (f2bf(b.y) << 16);
    o.w = f2bf(b.z) | (f2bf(b.w) << 16);
    ((uint4*)dst)[i] = o;
}

// three equal-size regions, contiguous destination
__global__ void cvt3_bf16_kernel(const float* __restrict__ s0, const float* __restrict__ s1,
                                 const float* __restrict__ s2, ushort* __restrict__ dst, int per8) {
    int i = blockIdx.x * 256 + threadIdx.x;
    if (i >= per8) return;
    int rgn = blockIdx.y;
    const float* s = (rgn == 0) ? s0 : (rgn == 1) ? s1 : s2;
    ushort* d = dst + (size_t)rgn * (size_t)per8 * 8;
    float4 a = ((const float4*)s)[2 * i];
    float4 b = ((const float4*)s)[2 * i + 1];
    uint4 o;
    o.x = f2bf(a.x) | (f2bf(a.y) << 16);
    o.y = f2bf(a.z) | (f2bf(a.w) << 16);
    o.z = f2bf(b.x) | (f2bf(b.y) << 16);
    o.w = f2bf(b.z) | (f2bf(b.w) << 16);
    ((uint4*)d)[i] = o;
}

// ---------------- router stage 1: logits/softmax/top-2 (no atomics) --------
__global__ void router_logits_kernel(const float* __restrict__ X,
                                     const float* __restrict__ Wr, int N,
                                     float* __restrict__ P, float* __restrict__ zz,
                                     int* __restrict__ idxA, float* __restrict__ wA)
{
    int wave = threadIdx.x >> 6;
    int lane = threadIdx.x & 63;
    int n = blockIdx.x * 4 + wave;

    float acc[8];
#pragma unroll
    for (int e = 0; e < 8; e++) acc[e] = 0.f;
    const float* xr = X + (size_t)n * H_DIM;
    for (int h = lane; h < H_DIM; h += 64) {
        float xv = xr[h];
#pragma unroll
        for (int e = 0; e < 8; e++) acc[e] += xv * Wr[e * H_DIM + h];
    }
#pragma unroll
    for (int off = 32; off > 0; off >>= 1) {
#pragma unroll
        for (int e = 0; e < 8; e++) acc[e] += __shfl_xor(acc[e], off, 64);
    }

    if (lane == 0) {
        float m = acc[0];
#pragma unroll
        for (int e = 1; e < 8; e++) m = fmaxf(m, acc[e]);
        float p[8];
        float s = 0.f;
#pragma unroll
        for (int e = 0; e < 8; e++) { p[e] = expf(acc[e] - m); s += p[e]; }
        float z = m + logf(s);
        float inv = 1.f / s;
#pragma unroll
        for (int e = 0; e < 8; e++) p[e] *= inv;
        // strict > keeps lowest index on ties (matches lax.top_k)
        int t1 = 0; float b1 = p[0];
#pragma unroll
        for (int e = 1; e < 8; e++) if (p[e] > b1) { b1 = p[e]; t1 = e; }
        int t2 = (t1 == 0) ? 1 : 0; float b2 = p[t2];
#pragma unroll
        for (int e = 0; e < 8; e++) if (e != t1 && p[e] > b2) { b2 = p[e]; t2 = e; }

        float wsum = b1 + b2 + EPSV;
#pragma unroll
        for (int e = 0; e < 8; e++) P[(size_t)n * 8 + e] = p[e];
        zz[n] = z * z;
        idxA[2 * n] = t1; idxA[2 * n + 1] = t2;
        wA[2 * n] = b1 / wsum; wA[2 * n + 1] = b2 / wsum;
    }
}

// ---------------- router stage 2: per-expert bucket scan (8 blocks x 1024) --
__global__ void bucket_scan_kernel(const int* __restrict__ idxA, const float* __restrict__ wA,
                                   int N, int* __restrict__ count, int* __restrict__ loadc_i,
                                   int* __restrict__ bucket_tok, float* __restrict__ wbkt)
{
    const int e = blockIdx.x;
    const int t = threadIdx.x;
    const int wave = t >> 6, lane = t & 63;
    __shared__ int wsum[16], wbase[16];
    __shared__ int s_run;
    __shared__ int s_load[16];
    if (t == 0) s_run = 0;
    int load1 = 0;

    for (int c0 = 0; c0 < 2 * N; c0 += 1024) {
        int i = c0 + t;
        int v = idxA[i];
        bool pred = (v == e);
        if (pred && ((i & 1) == 0)) load1++;
        unsigned long long mask = __ballot(pred);
        int prefix = __popcll(mask & ((1ull << lane) - 1ull));
        if (lane == 0) wsum[wave] = __popcll(mask);
        __syncthreads();
        if (t == 0) {
            int b = s_run;
            for (int w2 = 0; w2 < 16; w2++) { wbase[w2] = b; b += wsum[w2]; }
            s_run = b;
        }
        __syncthreads();
        if (pred) {
            int pos = wbase[wave] + prefix;
            bucket_tok[(size_t)e * N + pos] = i >> 1;
            wbkt[(size_t)e * N + pos] = wA[i];
        }
    }
#pragma unroll
    for (int off = 32; off > 0; off >>= 1) load1 += __shfl_down(load1, off, 64);
    if (lane == 0) s_load[wave] = load1;
    __syncthreads();
    if (t == 0) {
        count[e] = s_run;
        int l = 0;
        for (int w2 = 0; w2 < 16; w2++) l += s_load[w2];
        loadc_i[e] = l;
    }
}

// ---------------- router stage 3: aux-loss reduction (1 block) -------------
__global__ void aux_reduce_kernel(const float* __restrict__ P, const float* __restrict__ zz,
                                  const int* __restrict__ loadc_i, int N,
                                  float* __restrict__ aux_out)
{
    __shared__ float s_imp[256];
    __shared__ float s_z[256];
    const int t = threadIdx.x;
    const int e = t & 7, c = t >> 3;
    float si = 0.f;
    for (int n = c; n < N; n += 32) si += P[(size_t)n * 8 + e];
    s_imp[t] = si;
    float sz = 0.f;
    for (int n = t; n < N; n += 256) sz += zz[n];
    s_z[t] = sz;
    __syncthreads();
    if (t < 8) {
        float tot = 0.f;
        for (int c2 = 0; c2 < 32; c2++) tot += s_imp[c2 * 8 + t];
        s_imp[t] = tot;
    }
    if (t == 8) {
        float z = 0.f;
        for (int i = 0; i < 256; i++) z += s_z[i];
        s_z[0] = z;
    }
    __syncthreads();
    if (t == 0) {
        float is = 0.f, ls = 0.f, impv[8], ldv[8];
        for (int e2 = 0; e2 < 8; e2++) {
            impv[e2] = s_imp[e2];
            ldv[e2] = (float)loadc_i[e2];
            is += impv[e2]; ls += ldv[e2];
        }
        float lb = 0.f;
        for (int e2 = 0; e2 < 8; e2++)
            lb += (impv[e2] / (is + EPSV)) * (ldv[e2] / (ls + EPSV));
        lb *= (float)E_NUM;
        float zl = 0.001f * (s_z[0] / (float)N);
        aux_out[0] = 0.01f * lb + zl;
    }
}

// ---------------- fused gate+up GEMM, 256x128 dual-output, 4-deep ring -----
// z=0..7 experts (gathered rows), z=8 shared.
// Sub-buffer = 32 K-cols. Per buffer b: Pg{dsA+dsBg, issue A(b+3), MFMA g},
// Pu{dsBu, issue B(b+3), drain b+1, MFMA u}. NB=32 buffers.
__global__ void __launch_bounds__(512, 2)
gemm_gateup(const ushort* __restrict__ Xb,
            const ushort* __restrict__ Wsg, const ushort* __restrict__ Wsu,
            const ushort* __restrict__ Weg, const ushort* __restrict__ Weu,
            const int* __restrict__ count, const int* __restrict__ bucket_tok,
            ushort* __restrict__ Hgu, int N)
{
    const int z = blockIdx.z;
    const bool shx = (z == 8);
    int cnt, base;
    if (shx) { cnt = N; base = 0; }
    else {
        cnt = count[z];
        base = N;
        for (int e = 0; e < z; e++) base += count[e];
    }
    const int m0 = blockIdx.y * 256;
    if (m0 >= cnt) return;
    const int f0 = blockIdx.x * 128;
    const ushort* Wg = shx ? Wsg : Weg + (size_t)z * F_DIM * H_DIM;
    const ushort* Wu = shx ? Wsu : Weu + (size_t)z * F_DIM * H_DIM;

    __shared__ int rows[256];
    __shared__ ushort As[4 * 8192];    // ring4 x [256][32]
    __shared__ ushort Bgs[4 * 4096];   // ring4 x [128][32]
    __shared__ ushort Bus[4 * 4096];

    const int t = threadIdx.x;
    if (t < 256) {
        int r = m0 + t;
        rows[t] = shx ? r : bucket_tok[(size_t)z * N + (r < cnt ? r : cnt - 1)];
    }
    __syncthreads();

    const int w = t >> 6, lane = t & 63;
    // staging: lane l covers row (l>>2), 16B chunk c=(l&3); source col slot
    // pre-swizzled so LDS (linear dest) holds phys slot = q ^ ((row>>1)&3).
    const int lrow = lane >> 2;
    const int srcoff = ((lane & 3) ^ ((lane >> 3) & 3)) * 8;   // elements
    const ushort* pa0 = Xb + (size_t)rows[w * 32 + lrow] * H_DIM + srcoff;
    const ushort* pa1 = Xb + (size_t)rows[w * 32 + 16 + lrow] * H_DIM + srcoff;
    const ushort* pg0 = Wg + (size_t)(f0 + w * 16 + lrow) * H_DIM + srcoff;
    const ushort* pu0 = Wu + (size_t)(f0 + w * 16 + lrow) * H_DIM + srcoff;
    const int adst = w * 1024;   // wave-uniform dests (elements)
    const int bdst = w * 512;

    const int wm = w >> 1, wn = w & 1;
    const int lm = lane & 15, quad = lane >> 4;
    const int sl = ((quad ^ ((lm >> 1) & 3)) << 3);  // swizzled read slot
    const int abase = wm * 2048 + lm * 32 + sl;
    const int bbase = wn * 2048 + lm * 32 + sl;

    f32x4 zero4 = {0.f, 0.f, 0.f, 0.f};
    f32x4 accg[4][4], accu[4][4];
#pragma unroll
    for (int i = 0; i < 4; i++)
#pragma unroll
        for (int j = 0; j < 4; j++) { accg[i][j] = zero4; accu[i][j] = zero4; }

    // prologue: issue buffers 0..2, drain buf0 (12 in flight -> 8)
#pragma unroll
    for (int b0 = 0; b0 < 3; b0++) {
        gload16(pa0 + b0 * 32, &As[b0 * 8192 + adst]);
        gload16(pa1 + b0 * 32, &As[b0 * 8192 + adst + 512]);
        gload16(pg0 + b0 * 32, &Bgs[b0 * 4096 + bdst]);
        gload16(pu0 + b0 * 32, &Bus[b0 * 4096 + bdst]);
    }
    asm volatile("s_waitcnt vmcnt(8)" ::: "memory");
    __builtin_amdgcn_s_barrier();

    for (int b = 0; b < 32; b++) {
        const int cs = (b & 3);
        const int is_ = (b + 3) & 3;
        const ushort* Ac  = &As[cs * 8192];
        const ushort* Bgc = &Bgs[cs * 4096];
        const ushort* Buc = &Bus[cs * 4096];
        const int kn = (b + 3) * 32;
        const bool more = (b < 29);
        bf16x8 af[4], fb[4];

        // -- Pg: read A+Bg frags of b; issue A(b+3); MFMA gate
#pragma unroll
        for (int i = 0; i < 4; i++) af[i] = *(const bf16x8*)&Ac[abase + i * 512];
#pragma unroll
        for (int j = 0; j < 4; j++) fb[j] = *(const bf16x8*)&Bgc[bbase + j * 512];
        if (more) {
            gload16(pa0 + kn, &As[is_ * 8192 + adst]);
            gload16(pa1 + kn, &As[is_ * 8192 + adst + 512]);
        }
        PHASE_SYNC_PRE();
#pragma unroll
        for (int i = 0; i < 4; i++)
#pragma unroll
            for (int j = 0; j < 4; j++) accg[i][j] = MFMA16(af[i], fb[j], accg[i][j]);
        PHASE_SYNC_POST();

        // -- Pu: read Bu frags of b; issue Bg,Bu(b+3); drain b+1; MFMA up
#pragma unroll
        for (int j = 0; j < 4; j++) fb[j] = *(const bf16x8*)&Buc[bbase + j * 512];
        if (more) {
            gload16(pg0 + kn, &Bgs[is_ * 4096 + bdst]);
            gload16(pu0 + kn, &Bus[is_ * 4096 + bdst]);
        }
        if (b <= 28)      { asm volatile("s_waitcnt vmcnt(8)" ::: "memory"); }
        else if (b == 29) { asm volatile("s_waitcnt vmcnt(4)" ::: "memory"); }
        else if (b == 30) { asm volatile("s_waitcnt vmcnt(0)" ::: "memory"); }
        PHASE_SYNC_PRE();
#pragma unroll
        for (int i = 0; i < 4; i++)
#pragma unroll
            for (int j = 0; j < 4; j++) accu[i][j] = MFMA16(af[i], fb[j], accu[i][j]);
        PHASE_SYNC_POST();
    }

    // epilogue: silu(g)*u -> Hgu
#pragma unroll
    for (int i = 0; i < 4; i++)
#pragma unroll
        for (int j = 0; j < 4; j++) {
            int rb = wm * 64 + i * 16 + quad * 4;
            int col = f0 + wn * 64 + j * 16 + lm;
#pragma unroll
            for (int r = 0; r < 4; r++) {
                int rl = rb + r;
                if (m0 + rl < cnt) {
                    float g = accg[i][j][r], u = accu[i][j][r];
                    float hv = g / (1.f + __expf(-g)) * u;
                    Hgu[(size_t)(base + m0 + rl) * F_DIM + col] = (ushort)f2bf(hv);
                }
            }
        }
}

// ---------------- fused down proj + combine, 256x128, 6-deep ring ----------
// z=0..7 experts (scaled, scattered via atomics), z=8 shared. NB=64 buffers,
// one phase each: {dsA+dsB, issue (b+5), drain b+1, 16 MFMA}.
__global__ void __launch_bounds__(512, 2)
gemm_down(const ushort* __restrict__ Hgu,
          const ushort* __restrict__ Wsd, const ushort* __restrict__ Wed,
          const int* __restrict__ count, const int* __restrict__ bucket_tok,
          const float* __restrict__ wbkt, float* __restrict__ Y, int N)
{
    const int z = blockIdx.z;
    const bool shx = (z == 8);
    int cnt, base;
    if (shx) { cnt = N; base = 0; }
    else {
        cnt = count[z];
        base = N;
        for (int e = 0; e < z; e++) base += count[e];
    }
    const int m0 = blockIdx.y * 256;
    if (m0 >= cnt) return;
    const int h0 = blockIdx.x * 128;
    const ushort* Wd = shx ? Wsd : Wed + (size_t)z * H_DIM * F_DIM;

    __shared__ int toks[256];
    __shared__ float wgt[256];
    __shared__ ushort As[6 * 8192];   // ring6 x [256][32]
    __shared__ ushort Bs[6 * 4096];   // ring6 x [128][32]

    const int t = threadIdx.x;
    if (t < 256) {
        int r = m0 + t, rr = (r < cnt) ? r : cnt - 1;
        toks[t] = shx ? r : bucket_tok[(size_t)z * N + rr];
        wgt[t]  = shx ? 1.f : wbkt[(size_t)z * N + rr];
    }

    const int w = t >> 6, lane = t & 63;
    const int lrow = lane >> 2;
    const int srcoff = ((lane & 3) ^ ((lane >> 3) & 3)) * 8;
    int ar0 = m0 + w * 32 + lrow;      if (ar0 >= cnt) ar0 = cnt - 1;
    int ar1 = m0 + w * 32 + 16 + lrow; if (ar1 >= cnt) ar1 = cnt - 1;
    const ushort* pA0 = Hgu + (size_t)(base + ar0) * F_DIM + srcoff;
    const ushort* pA1 = Hgu + (size_t)(base + ar1) * F_DIM + srcoff;
    const ushort* pB0 = Wd + (size_t)(h0 + w * 16 + lrow) * F_DIM + srcoff;
    const int adst = w * 1024;
    const int bdst = w * 512;

    const int wm = w >> 1, wn = w & 1;
    const int lm = lane & 15, quad = lane >> 4;
    const int sl = ((quad ^ ((lm >> 1) & 3)) << 3);
    const int abase = wm * 2048 + lm * 32 + sl;
    const int bbase = wn * 2048 + lm * 32 + sl;

    f32x4 zero4 = {0.f, 0.f, 0.f, 0.f};
    f32x4 acc[4][4];
#pragma unroll
    for (int i = 0; i < 4; i++)
#pragma unroll
        for (int j = 0; j < 4; j++) acc[i][j] = zero4;

    // prologue: issue buffers 0..4 (15 loads), drain buf0 -> 12
#pragma unroll
    for (int b0 = 0; b0 < 5; b0++) {
        gload16(pA0 + b0 * 32, &As[b0 * 8192 + adst]);
        gload16(pA1 + b0 * 32, &As[b0 * 8192 + adst + 512]);
        gload16(pB0 + b0 * 32, &Bs[b0 * 4096 + bdst]);
    }
    asm volatile("s_waitcnt vmcnt(12)" ::: "memory");
    __builtin_amdgcn_s_barrier();

    int cs = 0, is_ = 5;
    for (int b = 0; b < 64; b++) {
        const ushort* Ac = &As[cs * 8192];
        const ushort* Bc = &Bs[cs * 4096];
        const int kn = (b + 5) * 32;
        const bool more = (b < 59);
        bf16x8 af[4], bf_[4];

#pragma unroll
        for (int i = 0; i < 4; i++) af[i] = *(const bf16x8*)&Ac[abase + i * 512];
#pragma unroll
        for (int j = 0; j < 4; j++) bf_[j] = *(const bf16x8*)&Bc[bbase + j * 512];
        if (more) {
            gload16(pA0 + kn, &As[is_ * 8192 + adst]);
            gload16(pA1 + kn, &As[is_ * 8192 + adst + 512]);
            gload16(pB0 + kn, &Bs[is_ * 4096 + bdst]);
        }
        if (b <= 58)      { asm volatile("s_waitcnt vmcnt(12)" ::: "memory"); }
        else if (b == 59) { asm volatile("s_waitcnt vmcnt(9)" ::: "memory"); }
        else if (b == 60) { asm volatile("s_waitcnt vmcnt(6)" ::: "memory"); }
        else if (b == 61) { asm volatile("s_waitcnt vmcnt(3)" ::: "memory"); }
        else if (b == 62) { asm volatile("s_waitcnt vmcnt(0)" ::: "memory"); }
        PHASE_SYNC_PRE();
#pragma unroll
        for (int i = 0; i < 4; i++)
#pragma unroll
            for (int j = 0; j < 4; j++) acc[i][j] = MFMA16(af[i], bf_[j], acc[i][j]);
        PHASE_SYNC_POST();

        cs = (cs == 5) ? 0 : cs + 1;
        is_ = (is_ == 5) ? 0 : is_ + 1;
    }

    // epilogue: scale by routing weight, atomic-accumulate into Y
#pragma unroll
    for (int i = 0; i < 4; i++)
#pragma unroll
        for (int j = 0; j < 4; j++) {
            int rb = wm * 64 + i * 16 + quad * 4;
            int col = h0 + wn * 64 + j * 16 + lm;
#pragma unroll
            for (int r = 0; r < 4; r++) {
                int rl = rb + r;
                if (m0 + rl < cnt)
                    unsafeAtomicAdd(&Y[(size_t)toks[rl] * H_DIM + col],
                                    acc[i][j][r] * wgt[rl]);
            }
        }
}

extern "C" void kernel_launch(void* const* d_in, const int* in_sizes, int n_in,
                              void* d_out, int out_size, void* d_ws, size_t ws_size,
                              hipStream_t stream)
{
    const float* x         = (const float*)d_in[0];
    const float* w_router  = (const float*)d_in[1];
    const float* w_sh_gate = (const float*)d_in[2];
    const float* w_sh_up   = (const float*)d_in[3];
    const float* w_sh_down = (const float*)d_in[4];
    const float* w_e_gate  = (const float*)d_in[5];
    const float* w_e_up    = (const float*)d_in[6];
    const float* w_e_down  = (const float*)d_in[7];
    float* out = (float*)d_out;
    int N = in_sizes[0] / H_DIM;  // 4096

    char* ws = (char*)d_ws;
    int*   count   = (int*)(ws + 0);
    int*   loadc_i = (int*)(ws + 32);
    size_t off = 256;
    int*   idxA = (int*)(ws + off);  off += (size_t)N * 2 * 4;
    float* wA   = (float*)(ws + off); off += (size_t)N * 2 * 4;
    int*   bucket_tok = (int*)(ws + off); off += (size_t)E_NUM * N * 4;
    float* wbkt = (float*)(ws + off); off += (size_t)E_NUM * N * 4;
    float* P    = (float*)(ws + off); off += (size_t)N * 8 * 4;
    float* zz   = (float*)(ws + off); off += (size_t)N * 4;
    off = (off + 255) & ~(size_t)255;
    ushort* Xb  = (ushort*)(ws + off); off += (size_t)N * H_DIM * 2;
    ushort* Wsh = (ushort*)(ws + off); off += (size_t)3 * F_DIM * H_DIM * 2;       // Wsg|Wsu|Wsd
    ushort* Wex = (ushort*)(ws + off); off += (size_t)3 * E_NUM * F_DIM * H_DIM * 2; // Weg|Weu|Wed
    ushort* Hgu = (ushort*)(ws + off); off += (size_t)3 * N * F_DIM * 2;           // sh rows | expert rows

    ushort* Wsg = Wsh;
    ushort* Wsu = Wsh + (size_t)F_DIM * H_DIM;
    ushort* Wsd = Wsh + (size_t)2 * F_DIM * H_DIM;
    ushort* Weg = Wex;
    ushort* Weu = Wex + (size_t)E_NUM * F_DIM * H_DIM;
    ushort* Wed = Wex + (size_t)2 * E_NUM * F_DIM * H_DIM;

    // zero the fp32 output accumulator
    {
        int n4 = N * H_DIM / 4;
        zero_kernel<<<(n4 + 255) / 256, 256, 0, stream>>>((float4*)out, n4);
    }

    // fp32 -> bf16 conversions (3 launches)
    {
        int n8x = N * H_DIM / 8;
        cvt_bf16_kernel<<<(n8x + 255) / 256, 256, 0, stream>>>(x, Xb, n8x);
        int per8s = F_DIM * H_DIM / 8;            // 262144
        cvt3_bf16_kernel<<<dim3(per8s / 256, 3), 256, 0, stream>>>(
            w_sh_gate, w_sh_up, w_sh_down, Wsh, per8s);
        int per8e = E_NUM * F_DIM * H_DIM / 8;    // 2097152
        cvt3_bf16_kernel<<<dim3(per8e / 256, 3), 256, 0, stream>>>(
            w_e_gate, w_e_up, w_e_down, Wex, per8e);
    }

    router_logits_kernel<<<N / 4, 256, 0, stream>>>(x, w_router, N, P, zz, idxA, wA);
    bucket_scan_kernel<<<E_NUM, 1024, 0, stream>>>(idxA, wA, N, count, loadc_i,
                                                   bucket_tok, wbkt);
    aux_reduce_kernel<<<1, 256, 0, stream>>>(P, zz, loadc_i, N, out + (size_t)N * H_DIM);

    gemm_gateup<<<dim3(F_DIM / 128, (N + 255) / 256, E_NUM + 1), 512, 0, stream>>>(
        Xb, Wsg, Wsu, Weg, Weu, count, bucket_tok, Hgu, N);
    gemm_down<<<dim3(H_DIM / 128, (N + 255) / 256, E_NUM + 1), 512, 0, stream>>>(
        Hgu, Wsd, Wed, count, bucket_tok, wbkt, out, N);
}

// Round 7
// 542.120 us; speedup vs baseline: 1.0591x; 1.0591x over previous
//
#include <hip/hip_runtime.h>
#include <math.h>

// MoE FFN: top-2 of 8 experts + shared expert, H=1024, F=2048, N=4096.
// Round 10: third attempt at R8 (two consecutive container/infra failures,
// no kernel data; source audited for hang-risk: none found — uniform barriers,
// satisfiable waits, memory-clobber-ordered load issues).
// R8 = R6 structure (best, 543us) minus sched_barrier(0) in phase sync.
//  - m141 mechanism: sched_barrier(0) order-pinning costs ~40% on GEMM loops.
//    Rule #18 needs it only for inline-asm ds_read; our frag loads are
//    compiler-visible, so the pin was gratuitous.
// Geometry (unchanged from R6): 256x128 dual-output gateup (2-deep BK=64,
// 129KB LDS), 256x128 down (3-deep, 146KB), T2 both-sides swizzle (conflicts=0),
// counted vmcnt, setprio around MFMA.

#define H_DIM 1024
#define F_DIM 2048
#define E_NUM 8
#define EPSV 1e-9f

typedef __bf16 bf16x8 __attribute__((ext_vector_type(8)));
typedef float f32x4 __attribute__((ext_vector_type(4)));

#define MFMA16(a, b, c) __builtin_amdgcn_mfma_f32_16x16x32_bf16(a, b, c, 0, 0, 0)

__device__ __forceinline__ unsigned f2bf(float f) {
    unsigned u = __float_as_uint(f);
    return (u + 0x7FFFu + ((u >> 16) & 1u)) >> 16;  // RNE
}

// async global->LDS, 16B per lane; lds ptr must be wave-uniform
__device__ __forceinline__ void gload16(const ushort* g, ushort* l) {
    __builtin_amdgcn_global_load_lds(
        (__attribute__((address_space(1))) void*)(void*)const_cast<ushort*>(g),
        (__attribute__((address_space(3))) void*)l, 16, 0, 0);
}

// m201-style phase sync: barrier + lgkm drain + setprio. NO sched_barrier(0)
// (m141: order-pinning regression; compiler-visible ds_reads don't need it).
#define PHASE_SYNC_PRE()                                      \
    __builtin_amdgcn_s_barrier();                             \
    asm volatile("s_waitcnt lgkmcnt(0)" ::: "memory");        \
    __builtin_amdgcn_s_setprio(1);

#define PHASE_SYNC_POST()                                     \
    __builtin_amdgcn_s_setprio(0);                            \
    __builtin_amdgcn_s_barrier();

// ---------------- Y zeroing (atomic-accumulate target) ----------------
__global__ void zero_kernel(float4* __restrict__ p, int n4) {
    int i = blockIdx.x * 256 + threadIdx.x;
    if (i < n4) p[i] = make_float4(0.f, 0.f, 0.f, 0.f);
}

// ---------------- fp32 -> bf16 conversion (8 elems/thread) ----------------
__global__ void cvt_bf16_kernel(const float* __restrict__ src, ushort* __restrict__ dst, int n8) {
    int i = blockIdx.x * 256 + threadIdx.x;
    if (i >= n8) return;
    float4 a = ((const float4*)src)[2 * i];
    float4 b = ((const float4*)src)[2 * i + 1];
    uint4 o;
    o.x = f2bf(a.x) | (f2bf(a.y) << 16);
    o.y = f2bf(a.z) | (f2bf(a.w) << 16);
    o.z = f2bf(b.x) | (f2bf(b.y) << 16);
    o.w = f2bf(b.z) | (f2bf(b.w) << 16);
    ((uint4*)dst)[i] = o;
}

// three equal-size regions, contiguous destination
__global__ void cvt3_bf16_kernel(const float* __restrict__ s0, const float* __restrict__ s1,
                                 const float* __restrict__ s2, ushort* __restrict__ dst, int per8) {
    int i = blockIdx.x * 256 + threadIdx.x;
    if (i >= per8) return;
    int rgn = blockIdx.y;
    const float* s = (rgn == 0) ? s0 : (rgn == 1) ? s1 : s2;
    ushort* d = dst + (size_t)rgn * (size_t)per8 * 8;
    float4 a = ((const float4*)s)[2 * i];
    float4 b = ((const float4*)s)[2 * i + 1];
    uint4 o;
    o.x = f2bf(a.x) | (f2bf(a.y) << 16);
    o.y = f2bf(a.z) | (f2bf(a.w) << 16);
    o.z = f2bf(b.x) | (f2bf(b.y) << 16);
    o.w = f2bf(b.z) | (f2bf(b.w) << 16);
    ((uint4*)d)[i] = o;
}

// ---------------- router stage 1: logits/softmax/top-2 (no atomics) --------
__global__ void router_logits_kernel(const float* __restrict__ X,
                                     const float* __restrict__ Wr, int N,
                                     float* __restrict__ P, float* __restrict__ zz,
                                     int* __restrict__ idxA, float* __restrict__ wA)
{
    int wave = threadIdx.x >> 6;
    int lane = threadIdx.x & 63;
    int n = blockIdx.x * 4 + wave;

    float acc[8];
#pragma unroll
    for (int e = 0; e < 8; e++) acc[e] = 0.f;
    const float* xr = X + (size_t)n * H_DIM;
    for (int h = lane; h < H_DIM; h += 64) {
        float xv = xr[h];
#pragma unroll
        for (int e = 0; e < 8; e++) acc[e] += xv * Wr[e * H_DIM + h];
    }
#pragma unroll
    for (int off = 32; off > 0; off >>= 1) {
#pragma unroll
        for (int e = 0; e < 8; e++) acc[e] += __shfl_xor(acc[e], off, 64);
    }

    if (lane == 0) {
        float m = acc[0];
#pragma unroll
        for (int e = 1; e < 8; e++) m = fmaxf(m, acc[e]);
        float p[8];
        float s = 0.f;
#pragma unroll
        for (int e = 0; e < 8; e++) { p[e] = expf(acc[e] - m); s += p[e]; }
        float z = m + logf(s);
        float inv = 1.f / s;
#pragma unroll
        for (int e = 0; e < 8; e++) p[e] *= inv;
        // strict > keeps lowest index on ties (matches lax.top_k)
        int t1 = 0; float b1 = p[0];
#pragma unroll
        for (int e = 1; e < 8; e++) if (p[e] > b1) { b1 = p[e]; t1 = e; }
        int t2 = (t1 == 0) ? 1 : 0; float b2 = p[t2];
#pragma unroll
        for (int e = 0; e < 8; e++) if (e != t1 && p[e] > b2) { b2 = p[e]; t2 = e; }

        float wsum = b1 + b2 + EPSV;
#pragma unroll
        for (int e = 0; e < 8; e++) P[(size_t)n * 8 + e] = p[e];
        zz[n] = z * z;
        idxA[2 * n] = t1; idxA[2 * n + 1] = t2;
        wA[2 * n] = b1 / wsum; wA[2 * n + 1] = b2 / wsum;
    }
}

// ---------------- router stage 2: per-expert bucket scan (8 blocks x 1024) --
__global__ void bucket_scan_kernel(const int* __restrict__ idxA, const float* __restrict__ wA,
                                   int N, int* __restrict__ count, int* __restrict__ loadc_i,
                                   int* __restrict__ bucket_tok, float* __restrict__ wbkt)
{
    const int e = blockIdx.x;
    const int t = threadIdx.x;
    const int wave = t >> 6, lane = t & 63;
    __shared__ int wsum[16], wbase[16];
    __shared__ int s_run;
    __shared__ int s_load[16];
    if (t == 0) s_run = 0;
    int load1 = 0;

    for (int c0 = 0; c0 < 2 * N; c0 += 1024) {
        int i = c0 + t;
        int v = idxA[i];
        bool pred = (v == e);
        if (pred && ((i & 1) == 0)) load1++;
        unsigned long long mask = __ballot(pred);
        int prefix = __popcll(mask & ((1ull << lane) - 1ull));
        if (lane == 0) wsum[wave] = __popcll(mask);
        __syncthreads();
        if (t == 0) {
            int b = s_run;
            for (int w2 = 0; w2 < 16; w2++) { wbase[w2] = b; b += wsum[w2]; }
            s_run = b;
        }
        __syncthreads();
        if (pred) {
            int pos = wbase[wave] + prefix;
            bucket_tok[(size_t)e * N + pos] = i >> 1;
            wbkt[(size_t)e * N + pos] = wA[i];
        }
    }
#pragma unroll
    for (int off = 32; off > 0; off >>= 1) load1 += __shfl_down(load1, off, 64);
    if (lane == 0) s_load[wave] = load1;
    __syncthreads();
    if (t == 0) {
        count[e] = s_run;
        int l = 0;
        for (int w2 = 0; w2 < 16; w2++) l += s_load[w2];
        loadc_i[e] = l;
    }
}

// ---------------- router stage 3: aux-loss reduction (1 block) -------------
__global__ void aux_reduce_kernel(const float* __restrict__ P, const float* __restrict__ zz,
                                  const int* __restrict__ loadc_i, int N,
                                  float* __restrict__ aux_out)
{
    __shared__ float s_imp[256];
    __shared__ float s_z[256];
    const int t = threadIdx.x;
    const int e = t & 7, c = t >> 3;
    float si = 0.f;
    for (int n = c; n < N; n += 32) si += P[(size_t)n * 8 + e];
    s_imp[t] = si;
    float sz = 0.f;
    for (int n = t; n < N; n += 256) sz += zz[n];
    s_z[t] = sz;
    __syncthreads();
    if (t < 8) {
        float tot = 0.f;
        for (int c2 = 0; c2 < 32; c2++) tot += s_imp[c2 * 8 + t];
        s_imp[t] = tot;
    }
    if (t == 8) {
        float z = 0.f;
        for (int i = 0; i < 256; i++) z += s_z[i];
        s_z[0] = z;
    }
    __syncthreads();
    if (t == 0) {
        float is = 0.f, ls = 0.f, impv[8], ldv[8];
        for (int e2 = 0; e2 < 8; e2++) {
            impv[e2] = s_imp[e2];
            ldv[e2] = (float)loadc_i[e2];
            is += impv[e2]; ls += ldv[e2];
        }
        float lb = 0.f;
        for (int e2 = 0; e2 < 8; e2++)
            lb += (impv[e2] / (is + EPSV)) * (ldv[e2] / (ls + EPSV));
        lb *= (float)E_NUM;
        float zl = 0.001f * (s_z[0] / (float)N);
        aux_out[0] = 0.01f * lb + zl;
    }
}

// ---------------- fused gate+up GEMM, 256x128 dual-output, 8-wave pipelined --
// z=0..7 experts (gathered rows), z=8 shared.
// Hgu rows: [0,N) = shared tokens, [N, 3N) = bucket-ordered expert rows.
// LDS tiles [256][64] (A) / [128][64] (Bg,Bu), XOR-swizzled slot = s ^ (row&7).
__global__ void __launch_bounds__(512, 2)
gemm_gateup(const ushort* __restrict__ Xb,
            const ushort* __restrict__ Wsg, const ushort* __restrict__ Wsu,
            const ushort* __restrict__ Weg, const ushort* __restrict__ Weu,
            const int* __restrict__ count, const int* __restrict__ bucket_tok,
            ushort* __restrict__ Hgu, int N)
{
    const int z = blockIdx.z;
    const bool shx = (z == 8);
    int cnt, base;
    if (shx) { cnt = N; base = 0; }
    else {
        cnt = count[z];
        base = N;
        for (int e = 0; e < z; e++) base += count[e];
    }
    const int m0 = blockIdx.y * 256;
    if (m0 >= cnt) return;
    const int f0 = blockIdx.x * 128;
    const ushort* Wg = shx ? Wsg : Weg + (size_t)z * F_DIM * H_DIM;
    const ushort* Wu = shx ? Wsu : Weu + (size_t)z * F_DIM * H_DIM;

    __shared__ int rows[256];
    __shared__ ushort As[2 * 16384];   // [buf][256][64]
    __shared__ ushort Bgs[2 * 8192];   // [buf][128][64]
    __shared__ ushort Bus[2 * 8192];

    const int t = threadIdx.x;
    if (t < 256) {
        int r = m0 + t;
        rows[t] = shx ? r : bucket_tok[(size_t)z * N + (r < cnt ? r : cnt - 1)];
    }
    __syncthreads();

    const int w = t >> 6, lane = t & 63;
    const int lr = lane >> 3, lc = lane & 7;
    const int srcs = (lc ^ lr) * 8;   // pre-swizzled source slot (elements)
    const ushort* pa[4];
#pragma unroll
    for (int l = 0; l < 4; l++)
        pa[l] = Xb + (size_t)rows[w * 32 + l * 8 + lr] * H_DIM + srcs;
    const ushort* pg[2]; const ushort* pu[2];
#pragma unroll
    for (int l = 0; l < 2; l++) {
        int fr = f0 + w * 16 + l * 8 + lr;
        pg[l] = Wg + (size_t)fr * H_DIM + srcs;
        pu[l] = Wu + (size_t)fr * H_DIM + srcs;
    }
    const int adst = w * 2048;   // wave-uniform LDS dest (elements)
    const int bdst = w * 1024;

    const int wm = w >> 1, wn = w & 1;
    const int lm = lane & 15, quad = lane >> 4;
    const int arow = (wm * 64 + lm) * 64;
    const int brow = (wn * 64 + lm) * 64;
    const int sx = lm & 7;
    const int sl0 = (quad ^ sx) * 8;        // kk=0 swizzled slot
    const int sl1 = ((4 + quad) ^ sx) * 8;  // kk=1 swizzled slot

    f32x4 zero4 = {0.f, 0.f, 0.f, 0.f};
    f32x4 accg[4][4], accu[4][4];
#pragma unroll
    for (int i = 0; i < 4; i++)
#pragma unroll
        for (int j = 0; j < 4; j++) { accg[i][j] = zero4; accu[i][j] = zero4; }

    // prologue: K-step 0 -> buffer 0, full drain
#pragma unroll
    for (int l = 0; l < 4; l++) gload16(pa[l], &As[adst + l * 512]);
#pragma unroll
    for (int l = 0; l < 2; l++) gload16(pg[l], &Bgs[bdst + l * 512]);
#pragma unroll
    for (int l = 0; l < 2; l++) gload16(pu[l], &Bus[bdst + l * 512]);
    __syncthreads();

    for (int ks = 0; ks < 16; ks++) {
        const int cb = ks & 1, nb = cb ^ 1;
        const ushort* Ac  = &As[cb * 16384];
        const ushort* Bgc = &Bgs[cb * 8192];
        const ushort* Buc = &Bus[cb * 8192];
        const int kn = (ks + 1) * 64;
        const bool more = ks < 15;
        bf16x8 a0[4], a1[4], fb[4];

        // -- phase 1: ds A(kk0)+Bg(kk0); issue A0,A1; vmcnt; MFMA g.kk0
#pragma unroll
        for (int i = 0; i < 4; i++) a0[i] = *(const bf16x8*)&Ac[arow + i * 1024 + sl0];
#pragma unroll
        for (int j = 0; j < 4; j++) fb[j] = *(const bf16x8*)&Bgc[brow + j * 1024 + sl0];
        if (more) {
            gload16(pa[0] + kn, &As[nb * 16384 + adst]);
            gload16(pa[1] + kn, &As[nb * 16384 + adst + 512]);
            asm volatile("s_waitcnt vmcnt(2)" ::: "memory");  // drain prev Bu
        } else {
            asm volatile("s_waitcnt vmcnt(0)" ::: "memory");
        }
        PHASE_SYNC_PRE();
#pragma unroll
        for (int i = 0; i < 4; i++)
#pragma unroll
            for (int j = 0; j < 4; j++) accg[i][j] = MFMA16(a0[i], fb[j], accg[i][j]);
        PHASE_SYNC_POST();

        // -- phase 2: ds Bu(kk0); issue Bg0,Bg1; MFMA u.kk0 (reuse a0)
#pragma unroll
        for (int j = 0; j < 4; j++) fb[j] = *(const bf16x8*)&Buc[brow + j * 1024 + sl0];
        if (more) {
            gload16(pg[0] + kn, &Bgs[nb * 8192 + bdst]);
            gload16(pg[1] + kn, &Bgs[nb * 8192 + bdst + 512]);
        }
        PHASE_SYNC_PRE();
#pragma unroll
        for (int i = 0; i < 4; i++)
#pragma unroll
            for (int j = 0; j < 4; j++) accu[i][j] = MFMA16(a0[i], fb[j], accu[i][j]);
        PHASE_SYNC_POST();

        // -- phase 3: ds A(kk1)+Bg(kk1); issue A2,A3; MFMA g.kk1
#pragma unroll
        for (int i = 0; i < 4; i++) a1[i] = *(const bf16x8*)&Ac[arow + i * 1024 + sl1];
#pragma unroll
        for (int j = 0; j < 4; j++) fb[j] = *(const bf16x8*)&Bgc[brow + j * 1024 + sl1];
        if (more) {
            gload16(pa[2] + kn, &As[nb * 16384 + adst + 1024]);
            gload16(pa[3] + kn, &As[nb * 16384 + adst + 1536]);
        }
        PHASE_SYNC_PRE();
#pragma unroll
        for (int i = 0; i < 4; i++)
#pragma unroll
            for (int j = 0; j < 4; j++) accg[i][j] = MFMA16(a1[i], fb[j], accg[i][j]);
        PHASE_SYNC_POST();

        // -- phase 4: ds Bu(kk1); issue Bu0,Bu1; vmcnt(2); MFMA u.kk1
#pragma unroll
        for (int j = 0; j < 4; j++) fb[j] = *(const bf16x8*)&Buc[brow + j * 1024 + sl1];
        if (more) {
            gload16(pu[0] + kn, &Bus[nb * 8192 + bdst]);
            gload16(pu[1] + kn, &Bus[nb * 8192 + bdst + 512]);
            asm volatile("s_waitcnt vmcnt(2)" ::: "memory");  // drain next A+Bg
        }
        PHASE_SYNC_PRE();
#pragma unroll
        for (int i = 0; i < 4; i++)
#pragma unroll
            for (int j = 0; j < 4; j++) accu[i][j] = MFMA16(a1[i], fb[j], accu[i][j]);
        PHASE_SYNC_POST();
    }

    // epilogue: silu(g)*u -> Hgu
#pragma unroll
    for (int i = 0; i < 4; i++)
#pragma unroll
        for (int j = 0; j < 4; j++) {
            int rb = wm * 64 + i * 16 + quad * 4;
            int col = f0 + wn * 64 + j * 16 + lm;
#pragma unroll
            for (int r = 0; r < 4; r++) {
                int rl = rb + r;
                if (m0 + rl < cnt) {
                    float g = accg[i][j][r], u = accu[i][j][r];
                    float hv = g / (1.f + __expf(-g)) * u;
                    Hgu[(size_t)(base + m0 + rl) * F_DIM + col] = (ushort)f2bf(hv);
                }
            }
        }
}

// ---------------- fused down proj + combine, 256x128, 3-deep pipeline -------
// z=0..7 experts (scaled, scattered via atomics), z=8 shared.
__global__ void __launch_bounds__(512, 2)
gemm_down(const ushort* __restrict__ Hgu,
          const ushort* __restrict__ Wsd, const ushort* __restrict__ Wed,
          const int* __restrict__ count, const int* __restrict__ bucket_tok,
          const float* __restrict__ wbkt, float* __restrict__ Y, int N)
{
    const int z = blockIdx.z;
    const bool shx = (z == 8);
    int cnt, base;
    if (shx) { cnt = N; base = 0; }
    else {
        cnt = count[z];
        base = N;
        for (int e = 0; e < z; e++) base += count[e];
    }
    const int m0 = blockIdx.y * 256;
    if (m0 >= cnt) return;
    const int h0 = blockIdx.x * 128;
    const ushort* Wd = shx ? Wsd : Wed + (size_t)z * H_DIM * F_DIM;

    __shared__ int toks[256];
    __shared__ float wgt[256];
    __shared__ ushort As[3 * 16384];   // [buf][256][64]
    __shared__ ushort Bs[3 * 8192];    // [buf][128][64]

    const int t = threadIdx.x;
    if (t < 256) {
        int r = m0 + t, rr = (r < cnt) ? r : cnt - 1;
        toks[t] = shx ? r : bucket_tok[(size_t)z * N + rr];
        wgt[t]  = shx ? 1.f : wbkt[(size_t)z * N + rr];
    }

    const int w = t >> 6, lane = t & 63;
    const int lr = lane >> 3, lc = lane & 7;
    const int srcs = (lc ^ lr) * 8;
    const ushort* pA0;
    const ushort* pA1;
    {
        int ar0 = m0 + w * 32 + lr;      if (ar0 >= cnt) ar0 = cnt - 1;
        int ar1 = m0 + w * 32 + 8 + lr;  if (ar1 >= cnt) ar1 = cnt - 1;
        pA0 = Hgu + (size_t)(base + ar0) * F_DIM + srcs;
        pA1 = Hgu + (size_t)(base + ar1) * F_DIM + srcs;
    }
    const ushort* pA2;
    const ushort* pA3;
    {
        int ar2 = m0 + w * 32 + 16 + lr; if (ar2 >= cnt) ar2 = cnt - 1;
        int ar3 = m0 + w * 32 + 24 + lr; if (ar3 >= cnt) ar3 = cnt - 1;
        pA2 = Hgu + (size_t)(base + ar2) * F_DIM + srcs;
        pA3 = Hgu + (size_t)(base + ar3) * F_DIM + srcs;
    }
    const ushort* pb0 = Wd + (size_t)(h0 + w * 16 + lr) * F_DIM + srcs;
    const ushort* pb1 = Wd + (size_t)(h0 + w * 16 + 8 + lr) * F_DIM + srcs;
    const int adst = w * 2048;
    const int bdst = w * 1024;

    const int wm = w >> 1, wn = w & 1;
    const int lm = lane & 15, quad = lane >> 4;
    const int arow = (wm * 64 + lm) * 64;
    const int brow = (wn * 64 + lm) * 64;
    const int sx = lm & 7;
    const int sl0 = (quad ^ sx) * 8;
    const int sl1 = ((4 + quad) ^ sx) * 8;

    f32x4 zero4 = {0.f, 0.f, 0.f, 0.f};
    f32x4 acc[4][4];
#pragma unroll
    for (int i = 0; i < 4; i++)
#pragma unroll
        for (int j = 0; j < 4; j++) acc[i][j] = zero4;

    // prologue: K0 -> buf0, K1 -> buf1, full drain
    gload16(pA0, &As[adst]);
    gload16(pA1, &As[adst + 512]);
    gload16(pA2, &As[adst + 1024]);
    gload16(pA3, &As[adst + 1536]);
    gload16(pb0, &Bs[bdst]);
    gload16(pb1, &Bs[bdst + 512]);
    gload16(pA0 + 64, &As[16384 + adst]);
    gload16(pA1 + 64, &As[16384 + adst + 512]);
    gload16(pA2 + 64, &As[16384 + adst + 1024]);
    gload16(pA3 + 64, &As[16384 + adst + 1536]);
    gload16(pb0 + 64, &Bs[8192 + bdst]);
    gload16(pb1 + 64, &Bs[8192 + bdst + 512]);
    __syncthreads();

    int cb = 0;
    for (int ks = 0; ks < 32; ks++) {
        const int sb = (cb == 0) ? 2 : cb - 1;   // (cb+2)%3
        const ushort* Ac = &As[cb * 16384];
        const ushort* Bc = &Bs[cb * 8192];
        const int kn2 = (ks + 2) * 64;
        const bool more = ks < 30;
        bf16x8 af[4], bf_[4];

        // -- phase 1: ds A(kk0)+B(kk0); issue A0..A2 of K+2; MFMA kk0
#pragma unroll
        for (int i = 0; i < 4; i++) af[i] = *(const bf16x8*)&Ac[arow + i * 1024 + sl0];
#pragma unroll
        for (int j = 0; j < 4; j++) bf_[j] = *(const bf16x8*)&Bc[brow + j * 1024 + sl0];
        if (more) {
            gload16(pA0 + kn2, &As[sb * 16384 + adst]);
            gload16(pA1 + kn2, &As[sb * 16384 + adst + 512]);
            gload16(pA2 + kn2, &As[sb * 16384 + adst + 1024]);
        }
        PHASE_SYNC_PRE();
#pragma unroll
        for (int i = 0; i < 4; i++)
#pragma unroll
            for (int j = 0; j < 4; j++) acc[i][j] = MFMA16(af[i], bf_[j], acc[i][j]);
        PHASE_SYNC_POST();

        // -- phase 2: ds A(kk1)+B(kk1); issue A3,B0,B1; vmcnt(6); MFMA kk1
#pragma unroll
        for (int i = 0; i < 4; i++) af[i] = *(const bf16x8*)&Ac[arow + i * 1024 + sl1];
#pragma unroll
        for (int j = 0; j < 4; j++) bf_[j] = *(const bf16x8*)&Bc[brow + j * 1024 + sl1];
        if (more) {
            gload16(pA3 + kn2, &As[sb * 16384 + adst + 1536]);
            gload16(pb0 + kn2, &Bs[sb * 8192 + bdst]);
            gload16(pb1 + kn2, &Bs[sb * 8192 + bdst + 512]);
            asm volatile("s_waitcnt vmcnt(6)" ::: "memory");  // drain K+1's 6
        } else {
            asm volatile("s_waitcnt vmcnt(0)" ::: "memory");
        }
        PHASE_SYNC_PRE();
#pragma unroll
        for (int i = 0; i < 4; i++)
#pragma unroll
            for (int j = 0; j < 4; j++) acc[i][j] = MFMA16(af[i], bf_[j], acc[i][j]);
        PHASE_SYNC_POST();

        cb = (cb == 2) ? 0 : cb + 1;
    }

    // epilogue: scale by routing weight, atomic-accumulate into Y
#pragma unroll
    for (int i = 0; i < 4; i++)
#pragma unroll
        for (int j = 0; j < 4; j++) {
            int rb = wm * 64 + i * 16 + quad * 4;
            int col = h0 + wn * 64 + j * 16 + lm;
#pragma unroll
            for (int r = 0; r < 4; r++) {
                int rl = rb + r;
                if (m0 + rl < cnt)
                    unsafeAtomicAdd(&Y[(size_t)toks[rl] * H_DIM + col],
                                    acc[i][j][r] * wgt[rl]);
            }
        }
}

extern "C" void kernel_launch(void* const* d_in, const int* in_sizes, int n_in,
                              void* d_out, int out_size, void* d_ws, size_t ws_size,
                              hipStream_t stream)
{
    const float* x         = (const float*)d_in[0];
    const float* w_router  = (const float*)d_in[1];
    const float* w_sh_gate = (const float*)d_in[2];
    const float* w_sh_up   = (const float*)d_in[3];
    const float* w_sh_down = (const float*)d_in[4];
    const float* w_e_gate  = (const float*)d_in[5];
    const float* w_e_up    = (const float*)d_in[6];
    const float* w_e_down  = (const float*)d_in[7];
    float* out = (float*)d_out;
    int N = in_sizes[0] / H_DIM;  // 4096

    char* ws = (char*)d_ws;
    int*   count   = (int*)(ws + 0);
    int*   loadc_i = (int*)(ws + 32);
    size_t off = 256;
    int*   idxA = (int*)(ws + off);  off += (size_t)N * 2 * 4;
    float* wA   = (float*)(ws + off); off += (size_t)N * 2 * 4;
    int*   bucket_tok = (int*)(ws + off); off += (size_t)E_NUM * N * 4;
    float* wbkt = (float*)(ws + off); off += (size_t)E_NUM * N * 4;
    float* P    = (float*)(ws + off); off += (size_t)N * 8 * 4;
    float* zz   = (float*)(ws + off); off += (size_t)N * 4;
    off = (off + 255) & ~(size_t)255;
    ushort* Xb  = (ushort*)(ws + off); off += (size_t)N * H_DIM * 2;
    ushort* Wsh = (ushort*)(ws + off); off += (size_t)3 * F_DIM * H_DIM * 2;       // Wsg|Wsu|Wsd
    ushort* Wex = (ushort*)(ws + off); off += (size_t)3 * E_NUM * F_DIM * H_DIM * 2; // Weg|Weu|Wed
    ushort* Hgu = (ushort*)(ws + off); off += (size_t)3 * N * F_DIM * 2;           // sh rows | expert rows

    ushort* Wsg = Wsh;
    ushort* Wsu = Wsh + (size_t)F_DIM * H_DIM;
    ushort* Wsd = Wsh + (size_t)2 * F_DIM * H_DIM;
    ushort* Weg = Wex;
    ushort* Weu = Wex + (size_t)E_NUM * F_DIM * H_DIM;
    ushort* Wed = Wex + (size_t)2 * E_NUM * F_DIM * H_DIM;

    // zero the fp32 output accumulator
    {
        int n4 = N * H_DIM / 4;
        zero_kernel<<<(n4 + 255) / 256, 256, 0, stream>>>((float4*)out, n4);
    }

    // fp32 -> bf16 conversions (3 launches)
    {
        int n8x = N * H_DIM / 8;
        cvt_bf16_kernel<<<(n8x + 255) / 256, 256, 0, stream>>>(x, Xb, n8x);
        int per8s = F_DIM * H_DIM / 8;            // 262144
        cvt3_bf16_kernel<<<dim3(per8s / 256, 3), 256, 0, stream>>>(
            w_sh_gate, w_sh_up, w_sh_down, Wsh, per8s);
        int per8e = E_NUM * F_DIM * H_DIM / 8;    // 2097152
        cvt3_bf16_kernel<<<dim3(per8e / 256, 3), 256, 0, stream>>>(
            w_e_gate, w_e_up, w_e_down, Wex, per8e);
    }

    router_logits_kernel<<<N / 4, 256, 0, stream>>>(x, w_router, N, P, zz, idxA, wA);
    bucket_scan_kernel<<<E_NUM, 1024, 0, stream>>>(idxA, wA, N, count, loadc_i,
                                                   bucket_tok, wbkt);
    aux_reduce_kernel<<<1, 256, 0, stream>>>(P, zz, loadc_i, N, out + (size_t)N * H_DIM);

    gemm_gateup<<<dim3(F_DIM / 128, (N + 255) / 256, E_NUM + 1), 512, 0, stream>>>(
        Xb, Wsg, Wsu, Weg, Weu, count, bucket_tok, Hgu, N);
    gemm_down<<<dim3(H_DIM / 128, (N + 255) / 256, E_NUM + 1), 512, 0, stream>>>(
        Hgu, Wsd, Wed, count, bucket_tok, wbkt, out, N);
}